// Round 3
// baseline (561.026 us; speedup 1.0000x reference)
//
#include <hip/hip_runtime.h>

static constexpr int B = 8, N = 1024, C = 48, H = 8, HD = 6, NT = B * N; // 8192 tokens
static constexpr int QKVO = 3 * C;   // 144
static constexpr int HID = 24, KB = 8;
static constexpr int C1 = 128;

#define DEVFN __device__ __forceinline__

DEVFN float wsum(float v) {
#pragma unroll
  for (int m = 32; m; m >>= 1) v += __shfl_xor(v, m, 64);
  return v;
}
DEVFN float wmax(float v) {
#pragma unroll
  for (int m = 32; m; m >>= 1) v = fmaxf(v, __shfl_xor(v, m, 64));
  return v;
}
DEVFN float gsum16(float v) {
#pragma unroll
  for (int m = 8; m; m >>= 1) v += __shfl_xor(v, m, 16);
  return v;
}
DEVFN float gmax16(float v) {
#pragma unroll
  for (int m = 8; m; m >>= 1) v = fmaxf(v, __shfl_xor(v, m, 16));
  return v;
}

// Cubic B-spline bases, GRID_SIZE=5, order=3, knots -2.2 + 0.4*j, j=0..11.
DEVFN void bspline8(float x, float* bs) {
  float b[11];
#pragma unroll
  for (int j = 0; j < 11; ++j) {
    float gj = -2.2f + 0.4f * j;
    float gj1 = -2.2f + 0.4f * (j + 1);
    b[j] = (x >= gj && x < gj1) ? 1.0f : 0.0f;
  }
#pragma unroll
  for (int j = 0; j < 10; ++j) {
    float gj = -2.2f + 0.4f * j;
    b[j] = (x - gj) * 2.5f * b[j] + ((gj + 0.8f) - x) * 2.5f * b[j + 1];
  }
#pragma unroll
  for (int j = 0; j < 9; ++j) {
    float gj = -2.2f + 0.4f * j;
    b[j] = (x - gj) * 1.25f * b[j] + ((gj + 1.2f) - x) * 1.25f * b[j + 1];
  }
#pragma unroll
  for (int j = 0; j < 8; ++j) {
    float gj = -2.2f + 0.4f * j;
    bs[j] = (x - gj) * (1.0f / 1.2f) * b[j] + ((gj + 1.6f) - x) * (1.0f / 1.2f) * b[j + 1];
  }
}

// ---------------- kernel 1: LN1 + QKV projection (2 tokens/wave) ---------
__global__ __launch_bounds__(256) void k_ln_qkv(
    const float* __restrict__ x, const float* __restrict__ g1, const float* __restrict__ b1,
    const float* __restrict__ wqkv, float* __restrict__ q, float* __restrict__ k,
    float* __restrict__ v) {
  __shared__ float wl[QKVO * 49];   // [o][i], stride 49 -> conflict-free
  __shared__ float nb[4][2][C];
  int tid = threadIdx.x;
  for (int e = tid; e < QKVO * C; e += 256) wl[(e / C) * 49 + (e % C)] = wqkv[e];
  int wave = tid >> 6, lane = tid & 63;
  int tok0 = blockIdx.x * 8 + wave * 2;
#pragma unroll
  for (int tt = 0; tt < 2; ++tt) {
    const float* xr = x + (tok0 + tt) * C;
    float xv = (lane < C) ? xr[lane] : 0.f;
    float s = wsum(xv), s2 = wsum(xv * xv);
    float mean = s * (1.f / C);
    float var = s2 * (1.f / C) - mean * mean;
    float rstd = rsqrtf(var + 1e-5f);
    if (lane < C) nb[wave][tt][lane] = (xv - mean) * rstd * g1[lane] + b1[lane];
  }
  __syncthreads();
  int b = tok0 >> 10, n0 = tok0 & 1023;
#pragma unroll
  for (int r = 0; r < 3; ++r) {
    int o = lane + (r << 6);
    if (o < QKVO) {
      float a0 = 0.f, a1 = 0.f;
#pragma unroll
      for (int i = 0; i < C; ++i) {
        float w = wl[o * 49 + i];
        a0 += nb[wave][0][i] * w;
        a1 += nb[wave][1][i] * w;
      }
      int ssel = o / C;
      int rem = o - ssel * C;
      int hh = rem / HD;
      int d = rem - hh * HD;
      float* dst = ssel == 0 ? q : (ssel == 1 ? k : v);
      dst[((b * H + hh) * N + n0) * HD + d] = a0;
      dst[((b * H + hh) * N + n0 + 1) * HD + d] = a1;
    }
  }
}

// ------- kernel 2: global attention + probs + local attention ------------
__global__ __launch_bounds__(256, 3) void k_gattn(
    const float* __restrict__ q, const float* __restrict__ k, const float* __restrict__ v,
    float* __restrict__ attn, float* __restrict__ xgl) {
  __shared__ float2 kt[3][N];   // [d-pair][kpos]
  __shared__ float2 vt[3][N];
  __shared__ float ob[64][6];   // per-row global-attn output
  int tid = threadIdx.x;
  int bh = blockIdx.x >> 4;     // 1024 blocks: 64 rows each
  int rb = blockIdx.x & 15;
  const float* kg = k + bh * N * HD;
  const float* vg = v + bh * N * HD;
  float* ktf = (float*)kt;
  float* vtf = (float*)vt;
  for (int e = tid; e < N * HD; e += 256) {
    int kp = e / 6, d = e - kp * 6;
    int a = (d >> 1) * 2048 + (kp << 1) + (d & 1);
    ktf[a] = kg[e];
    vtf[a] = vg[e];
  }
  __syncthreads();
  int wave = tid >> 6, lane = tid & 63;
  const float scl = 0.40824829046386301637f;  // 6^-0.5
  int b = bh >> 3, hh = bh & 7;
  int r0 = rb * 64 + wave * 16;
  // ---- phase 1: global attention, 4 tiles of 4 rows per wave ----
#pragma unroll 1
  for (int t4 = 0; t4 < 4; ++t4) {
    int qbase = r0 + t4 * 4;
    float2 qr[4][3];
#pragma unroll
    for (int rj = 0; rj < 4; ++rj) {
      const float2* qp = (const float2*)(q + (bh * N + qbase + rj) * HD);
      qr[rj][0] = qp[0]; qr[rj][1] = qp[1]; qr[rj][2] = qp[2];
    }
    float sv[4][16];
    float mx[4] = {-1e30f, -1e30f, -1e30f, -1e30f};
#pragma unroll
    for (int it = 0; it < 16; ++it) {
      int kp = lane + (it << 6);
      float2 k0 = kt[0][kp], k1 = kt[1][kp], k2 = kt[2][kp];
#pragma unroll
      for (int rj = 0; rj < 4; ++rj) {
        float dp = qr[rj][0].x * k0.x + qr[rj][0].y * k0.y + qr[rj][1].x * k1.x +
                   qr[rj][1].y * k1.y + qr[rj][2].x * k2.x + qr[rj][2].y * k2.y;
        sv[rj][it] = dp * scl;
        mx[rj] = fmaxf(mx[rj], sv[rj][it]);
      }
    }
#pragma unroll
    for (int rj = 0; rj < 4; ++rj) mx[rj] = wmax(mx[rj]);
    float sum[4] = {0.f, 0.f, 0.f, 0.f};
#pragma unroll
    for (int it = 0; it < 16; ++it) {
#pragma unroll
      for (int rj = 0; rj < 4; ++rj) {
        sv[rj][it] = __expf(sv[rj][it] - mx[rj]);
        sum[rj] += sv[rj][it];
      }
    }
#pragma unroll
    for (int rj = 0; rj < 4; ++rj) sum[rj] = 1.f / wsum(sum[rj]);
#pragma unroll
    for (int it = 0; it < 16; ++it) {
#pragma unroll
      for (int rj = 0; rj < 4; ++rj) sv[rj][it] *= sum[rj];
    }
    float acc[4][6];
#pragma unroll
    for (int rj = 0; rj < 4; ++rj)
#pragma unroll
      for (int d = 0; d < 6; ++d) acc[rj][d] = 0.f;
#pragma unroll
    for (int it = 0; it < 16; ++it) {
      int kp = lane + (it << 6);
      float2 v0 = vt[0][kp], v1 = vt[1][kp], v2 = vt[2][kp];
#pragma unroll
      for (int rj = 0; rj < 4; ++rj) {
        float p = sv[rj][it];
        __builtin_nontemporal_store(p, attn + (size_t)(bh * N + qbase + rj) * N + kp);
        acc[rj][0] += p * v0.x; acc[rj][1] += p * v0.y; acc[rj][2] += p * v1.x;
        acc[rj][3] += p * v1.y; acc[rj][4] += p * v2.x; acc[rj][5] += p * v2.y;
      }
    }
#pragma unroll
    for (int rj = 0; rj < 4; ++rj) {
#pragma unroll
      for (int d = 0; d < 6; ++d) acc[rj][d] = wsum(acc[rj][d]);
      if (lane == 0) {
        int li = wave * 16 + t4 * 4 + rj;
#pragma unroll
        for (int d = 0; d < 6; ++d) ob[li][d] = acc[rj][d];
      }
    }
  }
  // ---- phase 2: local window attention; wave's 16 rows == one window ----
  int n0 = r0;                  // window base
  int kk = lane & 15, g = lane >> 4;
  float kv[6], vv[6];
#pragma unroll
  for (int d = 0; d < 6; ++d) {
    int a = (d >> 1) * 2048 + ((n0 + kk) << 1) + (d & 1);
    kv[d] = ktf[a];
    vv[d] = vtf[a];
  }
#pragma unroll
  for (int pass = 0; pass < 4; ++pass) {
    int qr2 = n0 + pass * 4 + g;
    const float* qp = q + (bh * N + qr2) * HD;
    float s = 0.f;
#pragma unroll
    for (int d = 0; d < 6; ++d) s += qp[d] * kv[d];
    s *= scl;
    float mx2 = gmax16(s);
    float p = __expf(s - mx2);
    float sum2 = gsum16(p);
    float inv = 1.f / sum2;
    float o[6];
#pragma unroll
    for (int d = 0; d < 6; ++d) o[d] = gsum16(p * vv[d]) * inv;
    if (kk == 0) {
      int li = wave * 16 + pass * 4 + g;
      float* dst = xgl + (size_t)(b * N + qr2) * C + hh * HD;
#pragma unroll
      for (int d = 0; d < 6; ++d) dst[d] = ob[li][d] + o[d];
    }
  }
}

// ------- kernel 3: proj + residual + LN2 + KAN1 + KAN2 + residual --------
__global__ __launch_bounds__(512) void k_mlp(
    const float* __restrict__ x, const float* __restrict__ xgl,
    const float* __restrict__ wp, const float* __restrict__ bp,
    const float* __restrict__ g2, const float* __restrict__ b2,
    const float* __restrict__ bw1, const float* __restrict__ sw1, const float* __restrict__ ss1,
    const float* __restrict__ bw2, const float* __restrict__ sw2, const float* __restrict__ ss2,
    float* __restrict__ x2) {
  __shared__ float wpl[C * 49];          // [o][i]
  __shared__ float bw1t[C * 25];         // [i][o], o<24
  __shared__ float ss1t[C * 25];
  __shared__ float sw1t[C * KB * 25];    // [i*8+k][o]
  __shared__ float bw2t[HID * 49];       // [i][o], o<48
  __shared__ float ss2t[HID * 49];
  __shared__ float sw2t[HID * KB * 49];  // [i*8+k][o]
  __shared__ float abuf[8][2][C];
  __shared__ float sil1[8][2][C];
  __shared__ float bas1[8][2][C][KB];
  __shared__ float sil2[8][2][HID];
  __shared__ float bas2[8][2][HID][KB];
  int tid = threadIdx.x;
  for (int e = tid; e < C * C; e += 512) wpl[(e / C) * 49 + (e % C)] = wp[e];
  for (int e = tid; e < HID * C; e += 512) {
    int o = e / C, i = e - o * C;
    bw1t[i * 25 + o] = bw1[e];
    ss1t[i * 25 + o] = ss1[e];
  }
  for (int e = tid; e < HID * C * KB; e += 512) {
    int o = e / (C * KB), r = e - o * (C * KB);
    sw1t[r * 25 + o] = sw1[e];
  }
  for (int e = tid; e < C * HID; e += 512) {
    int o = e / HID, i = e - o * HID;
    bw2t[i * 49 + o] = bw2[e];
    ss2t[i * 49 + o] = ss2[e];
  }
  for (int e = tid; e < C * HID * KB; e += 512) {
    int o = e / (HID * KB), r = e - o * (HID * KB);
    sw2t[r * 49 + o] = sw2[e];
  }
  __syncthreads();
  int wave = tid >> 6, lane = tid & 63;
  int tok0 = blockIdx.x * 16 + wave * 2;
  float x1v[2];
  // ---- phase A: proj + residual + LN2 + bases (per token) ----
#pragma unroll
  for (int tt = 0; tt < 2; ++tt) {
    int tok = tok0 + tt;
    float acc = 0.f, xin = 0.f;
    if (lane < C) {
      abuf[wave][tt][lane] = xgl[tok * C + lane];
      xin = x[tok * C + lane];
    }
    if (lane < C) {
      acc = bp[lane];
#pragma unroll
      for (int i = 0; i < C; ++i) acc += abuf[wave][tt][i] * wpl[lane * 49 + i];
    }
    float xv = (lane < C) ? xin + acc : 0.f;
    x1v[tt] = xv;
    float s = wsum(xv), s2 = wsum(xv * xv);
    float mean = s * (1.f / C), var = s2 * (1.f / C) - mean * mean;
    float rstd = rsqrtf(var + 1e-5f);
    if (lane < C) {
      float n2v = (xv - mean) * rstd * g2[lane] + b2[lane];
      sil1[wave][tt][lane] = n2v / (1.f + __expf(-n2v));
      float bs[KB];
      bspline8(n2v, bs);
#pragma unroll
      for (int kk = 0; kk < KB; ++kk) bas1[wave][tt][lane][kk] = bs[kk];
    }
  }
  // ---- phase B: KAN1 (48 -> 24), both tokens share weight reads ----
  int o = lane & 31, hf = lane >> 5;
  float h0 = 0.f, h1 = 0.f;
  if (o < HID) {
#pragma unroll 4
    for (int ii = 0; ii < 24; ++ii) {
      int i = hf * 24 + ii;
      float bwv = bw1t[i * 25 + o], ssv = ss1t[i * 25 + o];
      float sp0 = 0.f, sp1 = 0.f;
#pragma unroll
      for (int kk = 0; kk < KB; ++kk) {
        float w = sw1t[(i * KB + kk) * 25 + o];
        sp0 += bas1[wave][0][i][kk] * w;
        sp1 += bas1[wave][1][i][kk] * w;
      }
      h0 += sil1[wave][0][i] * bwv + ssv * sp0;
      h1 += sil1[wave][1][i] * bwv + ssv * sp1;
    }
  }
  h0 += __shfl_xor(h0, 32, 64);
  h1 += __shfl_xor(h1, 32, 64);
  if (lane < HID) {
    float hv[2] = {h0, h1};
#pragma unroll
    for (int tt = 0; tt < 2; ++tt) {
      sil2[wave][tt][lane] = hv[tt] / (1.f + __expf(-hv[tt]));
      float bs[KB];
      bspline8(hv[tt], bs);
#pragma unroll
      for (int kk = 0; kk < KB; ++kk) bas2[wave][tt][lane][kk] = bs[kk];
    }
  }
  // ---- phase C: KAN2 (24 -> 48) + residual ----
  if (lane < C) {
    float a0 = 0.f, a1 = 0.f;
#pragma unroll 4
    for (int i = 0; i < HID; ++i) {
      float bwv = bw2t[i * 49 + lane], ssv = ss2t[i * 49 + lane];
      float sp0 = 0.f, sp1 = 0.f;
#pragma unroll
      for (int kk = 0; kk < KB; ++kk) {
        float w = sw2t[(i * KB + kk) * 49 + lane];
        sp0 += bas2[wave][0][i][kk] * w;
        sp1 += bas2[wave][1][i][kk] * w;
      }
      a0 += sil2[wave][0][i] * bwv + ssv * sp0;
      a1 += sil2[wave][1][i] * bwv + ssv * sp1;
    }
    x2[(size_t)tok0 * C + lane] = x1v[0] + a0;
    x2[(size_t)(tok0 + 1) * C + lane] = x1v[1] + a1;
  }
}

// ---------------- kernel 4: conv1 (48 -> 128, k=3) -----------------------
__global__ __launch_bounds__(256) void k_conv1(
    const float* __restrict__ x, const float* __restrict__ w1, const float* __restrict__ bc1,
    float* __restrict__ h1) {
  __shared__ float wt[72 * C1];  // [i3][o] for one i-half
  __shared__ float xr[18 * C];
  int tid = threadIdx.x;
  int b = blockIdx.x >> 6;
  int t0 = (blockIdx.x & 63) << 4;
  for (int e = tid; e < 18 * C; e += 256) {
    int r = e / C, c = e - r * C;
    int n = t0 - 1 + r;
    xr[e] = (n >= 0 && n < N) ? x[(b * N + n) * C + c] : 0.f;
  }
  int wave = tid >> 6, lane = tid & 63;
  int tb = wave << 2;
  float acc0[4] = {0, 0, 0, 0}, acc1[4] = {0, 0, 0, 0};
  for (int hf = 0; hf < 2; ++hf) {
    __syncthreads();
    for (int e = tid; e < 72 * C1; e += 256) {
      int i3 = e >> 7, o = e & 127;
      int ii = i3 / 3, dk = i3 - ii * 3;
      wt[e] = w1[(o * C + hf * 24 + ii) * 3 + dk];
    }
    __syncthreads();
#pragma unroll 4
    for (int ii = 0; ii < 24; ++ii) {
      float xv[6];
#pragma unroll
      for (int j = 0; j < 6; ++j) xv[j] = xr[(tb + j) * C + hf * 24 + ii];
#pragma unroll
      for (int dk = 0; dk < 3; ++dk) {
        float w0 = wt[(ii * 3 + dk) * C1 + lane];
        float w1v = wt[(ii * 3 + dk) * C1 + 64 + lane];
#pragma unroll
        for (int tt = 0; tt < 4; ++tt) {
          float xi = xv[tt + dk];
          acc0[tt] += xi * w0;
          acc1[tt] += xi * w1v;
        }
      }
    }
  }
  float bb0 = bc1[lane], bb1 = bc1[64 + lane];
#pragma unroll
  for (int tt = 0; tt < 4; ++tt) {
    int n = t0 + tb + tt;
    h1[(b * N + n) * C1 + lane] = acc0[tt] + bb0;
    h1[(b * N + n) * C1 + 64 + lane] = acc1[tt] + bb1;
  }
}

// ---------------- kernel 5: conv2 + LN(g1,b1) + sc*h + x2 -> out ---------
__global__ __launch_bounds__(256) void k_conv2out(
    const float* __restrict__ h1, const float* __restrict__ w3, const float* __restrict__ bc3,
    const float* __restrict__ g1, const float* __restrict__ b1,
    const float* __restrict__ x2, const float* __restrict__ scp,
    float* __restrict__ out) {
  __shared__ float wt[192 * C + 16];  // [i3][c] for one i-half (+pad)
  __shared__ float hr[18 * C1];
  int tid = threadIdx.x;
  int b = blockIdx.x >> 6;
  int t0 = (blockIdx.x & 63) << 4;
  for (int e = tid; e < 18 * C1; e += 256) {
    int r = e >> 7, c = e & 127;
    int n = t0 - 1 + r;
    hr[e] = (n >= 0 && n < N) ? h1[(b * N + n) * C1 + c] : 0.f;
  }
  int wave = tid >> 6, lane = tid & 63;
  int tb = wave << 2;
  float acc[4] = {0, 0, 0, 0};
  for (int hf = 0; hf < 2; ++hf) {
    __syncthreads();
    for (int e = tid; e < 192 * C; e += 256) {
      int i3 = e / C, c = e - i3 * C;
      int ii = i3 / 3, dk = i3 - ii * 3;
      wt[e] = w3[(c * C1 + hf * 64 + ii) * 3 + dk];
    }
    __syncthreads();
#pragma unroll 4
    for (int ii = 0; ii < 64; ++ii) {
      float xv[6];
#pragma unroll
      for (int j = 0; j < 6; ++j) xv[j] = hr[(tb + j) * C1 + hf * 64 + ii];
#pragma unroll
      for (int dk = 0; dk < 3; ++dk) {
        float w = wt[(ii * 3 + dk) * C + lane];
#pragma unroll
        for (int tt = 0; tt < 4; ++tt) acc[tt] += xv[tt + dk] * w;
      }
    }
  }
  float sc0 = scp[0];
#pragma unroll
  for (int tt = 0; tt < 4; ++tt) {
    int n = t0 + tb + tt;
    float val = (lane < C) ? acc[tt] + bc3[lane] : 0.f;
    float s = wsum(val), s2 = wsum(val * val);
    float mean = s * (1.f / C), var = s2 * (1.f / C) - mean * mean;
    float rstd = rsqrtf(var + 1e-5f);
    if (lane < C) {
      float hn = (val - mean) * rstd * g1[lane] + b1[lane];
      out[(b * N + n) * C + lane] = sc0 * hn + x2[(size_t)(b * N + n) * C + lane];
    }
  }
}

extern "C" void kernel_launch(void* const* d_in, const int* in_sizes, int n_in,
                              void* d_out, int out_size, void* d_ws, size_t ws_size,
                              hipStream_t stream) {
  (void)in_sizes; (void)n_in; (void)out_size; (void)ws_size;
  const float* x    = (const float*)d_in[0];
  const float* g1   = (const float*)d_in[1];
  const float* b1   = (const float*)d_in[2];
  const float* wqkv = (const float*)d_in[3];
  const float* wp   = (const float*)d_in[4];
  const float* bp   = (const float*)d_in[5];
  const float* g2   = (const float*)d_in[6];
  const float* b2   = (const float*)d_in[7];
  const float* bw1  = (const float*)d_in[8];
  const float* sw1  = (const float*)d_in[9];
  const float* ss1  = (const float*)d_in[10];
  const float* bw2  = (const float*)d_in[11];
  const float* sw2  = (const float*)d_in[12];
  const float* ss2  = (const float*)d_in[13];
  const float* w1   = (const float*)d_in[14];
  const float* bc1  = (const float*)d_in[15];
  const float* w3   = (const float*)d_in[16];
  const float* bc3  = (const float*)d_in[17];
  const float* scp  = (const float*)d_in[18];

  float* out  = (float*)d_out;
  float* attn = out + (size_t)NT * C;  // out first, then attn_global

  float* ws   = (float*)d_ws;
  float* q    = ws;                 // 393216
  float* k    = ws + 393216;
  float* v    = ws + 786432;
  float* xgl  = ws + 1179648;       // global+local attn output (B,N,C)
  float* x2   = ws + 1572864;
  float* h1   = ws + 1966080;       // (B,N,128) = 1048576

  k_ln_qkv<<<NT / 8, 256, 0, stream>>>(x, g1, b1, wqkv, q, k, v);
  k_gattn<<<B * H * 16, 256, 0, stream>>>(q, k, v, attn, xgl);
  k_mlp<<<NT / 16, 512, 0, stream>>>(x, xgl, wp, bp, g2, b2,
                                     bw1, sw1, ss1, bw2, sw2, ss2, x2);
  k_conv1<<<512, 256, 0, stream>>>(x, w1, bc1, h1);
  k_conv2out<<<512, 256, 0, stream>>>(h1, w3, bc3, g1, b1, x2, scp, out);
}

// Round 6
// 483.339 us; speedup vs baseline: 1.1607x; 1.1607x over previous
//
#include <hip/hip_runtime.h>

static constexpr int B = 8, N = 1024, C = 48, H = 8, HD = 6, NT = B * N; // 8192 tokens
static constexpr int QKVO = 3 * C;   // 144
static constexpr int HID = 24, KB = 8;
static constexpr int C1 = 128;

typedef float vfloat2 __attribute__((ext_vector_type(2)));  // clang-native, NT-store OK

#define DEVFN __device__ __forceinline__

DEVFN float wsum(float v) {
#pragma unroll
  for (int m = 32; m; m >>= 1) v += __shfl_xor(v, m, 64);
  return v;
}
DEVFN float gsum16(float v) {
#pragma unroll
  for (int m = 8; m; m >>= 1) v += __shfl_xor(v, m, 16);
  return v;
}
DEVFN float gmax16(float v) {
#pragma unroll
  for (int m = 8; m; m >>= 1) v = fmaxf(v, __shfl_xor(v, m, 16));
  return v;
}

// Cubic B-spline bases, GRID_SIZE=5, order=3, knots -2.2 + 0.4*j, j=0..11.
DEVFN void bspline8(float x, float* bs) {
  float b[11];
#pragma unroll
  for (int j = 0; j < 11; ++j) {
    float gj = -2.2f + 0.4f * j;
    float gj1 = -2.2f + 0.4f * (j + 1);
    b[j] = (x >= gj && x < gj1) ? 1.0f : 0.0f;
  }
#pragma unroll
  for (int j = 0; j < 10; ++j) {
    float gj = -2.2f + 0.4f * j;
    b[j] = (x - gj) * 2.5f * b[j] + ((gj + 0.8f) - x) * 2.5f * b[j + 1];
  }
#pragma unroll
  for (int j = 0; j < 9; ++j) {
    float gj = -2.2f + 0.4f * j;
    b[j] = (x - gj) * 1.25f * b[j] + ((gj + 1.2f) - x) * 1.25f * b[j + 1];
  }
#pragma unroll
  for (int j = 0; j < 8; ++j) {
    float gj = -2.2f + 0.4f * j;
    bs[j] = (x - gj) * (1.0f / 1.2f) * b[j] + ((gj + 1.6f) - x) * (1.0f / 1.2f) * b[j + 1];
  }
}

// ---------------- kernel 1: LN1 + QKV projection (2 tokens/wave) ---------
__global__ __launch_bounds__(256) void k_ln_qkv(
    const float* __restrict__ x, const float* __restrict__ g1, const float* __restrict__ b1,
    const float* __restrict__ wqkv, float* __restrict__ q, float* __restrict__ k,
    float* __restrict__ v) {
  __shared__ float wl[QKVO * 49];   // [o][i], stride 49 -> conflict-free
  __shared__ float nb[4][2][C];
  int tid = threadIdx.x;
  for (int e = tid; e < QKVO * C; e += 256) wl[(e / C) * 49 + (e % C)] = wqkv[e];
  int wave = tid >> 6, lane = tid & 63;
  int tok0 = blockIdx.x * 8 + wave * 2;
#pragma unroll
  for (int tt = 0; tt < 2; ++tt) {
    const float* xr = x + (tok0 + tt) * C;
    float xv = (lane < C) ? xr[lane] : 0.f;
    float s = wsum(xv), s2 = wsum(xv * xv);
    float mean = s * (1.f / C);
    float var = s2 * (1.f / C) - mean * mean;
    float rstd = rsqrtf(var + 1e-5f);
    if (lane < C) nb[wave][tt][lane] = (xv - mean) * rstd * g1[lane] + b1[lane];
  }
  __syncthreads();
  int b = tok0 >> 10, n0 = tok0 & 1023;
#pragma unroll
  for (int r = 0; r < 3; ++r) {
    int o = lane + (r << 6);
    if (o < QKVO) {
      float a0 = 0.f, a1 = 0.f;
#pragma unroll
      for (int i = 0; i < C; ++i) {
        float w = wl[o * 49 + i];
        a0 += nb[wave][0][i] * w;
        a1 += nb[wave][1][i] * w;
      }
      int ssel = o / C;
      int rem = o - ssel * C;
      int hh = rem / HD;
      int d = rem - hh * HD;
      float* dst = ssel == 0 ? q : (ssel == 1 ? k : v);
      dst[((b * H + hh) * N + n0) * HD + d] = a0;
      dst[((b * H + hh) * N + n0 + 1) * HD + d] = a1;
    }
  }
}

// ------- kernel 2: global attention + probs + local attention ------------
__global__ __launch_bounds__(256) void k_gattn(
    const float* __restrict__ q, const float* __restrict__ k, const float* __restrict__ v,
    float* __restrict__ attn, float* __restrict__ xgl) {
  __shared__ float2 kt[3][N];   // kt[dp][kp] = {K[kp][2dp], K[kp][2dp+1]}
  __shared__ float2 vt[3][N];
  __shared__ float ob[64][6];   // per-row global-attn output
  int tid = threadIdx.x;
  int bh = blockIdx.x >> 4;     // 1024 blocks: 64 rows each
  int rb = blockIdx.x & 15;
  const float* kg = k + bh * N * HD;
  const float* vg = v + bh * N * HD;
  float* ktf = (float*)kt;
  float* vtf = (float*)vt;
  for (int e = tid; e < N * HD; e += 256) {
    int kp = e / 6, d = e - kp * 6;
    int a = (d >> 1) * 2048 + (kp << 1) + (d & 1);
    ktf[a] = kg[e];
    vtf[a] = vg[e];
  }
  __syncthreads();
  int wave = tid >> 6, lane = tid & 63;
  const float scl = 0.40824829046386301637f;  // 6^-0.5
  int b = bh >> 3, hh = bh & 7;
  int r0 = rb * 64 + wave * 16;
  const float4* kt4 = (const float4*)ktf;  // [dp*512 + j]: dims(2dp,2dp+1) x pos(2j,2j+1)
  const float4* vt4 = (const float4*)vtf;
  // ---- phase 1: global attention, 8 tiles of 2 rows; 2 k-pos per lane ----
#pragma unroll 1
  for (int t2 = 0; t2 < 8; ++t2) {
    int qbase = r0 + t2 * 2;
    float2 qa[3], qb[3];
    {
      const float2* qp = (const float2*)(q + (bh * N + qbase) * HD);
      qa[0] = qp[0]; qa[1] = qp[1]; qa[2] = qp[2];
      qp = (const float2*)(q + (bh * N + qbase + 1) * HD);
      qb[0] = qp[0]; qb[1] = qp[1]; qb[2] = qp[2];
#pragma unroll
      for (int d = 0; d < 3; ++d) {
        qa[d].x *= scl; qa[d].y *= scl;
        qb[d].x *= scl; qb[d].y *= scl;
      }
    }
    float sva[16], svb[16];
    float suma = 0.f, sumb = 0.f;
#pragma unroll
    for (int it = 0; it < 8; ++it) {
      int j = (it << 6) + lane;
      float4 k0 = kt4[j], k1 = kt4[512 + j], k2 = kt4[1024 + j];
      float da0 = qa[0].x * k0.x + qa[0].y * k0.y + qa[1].x * k1.x + qa[1].y * k1.y +
                  qa[2].x * k2.x + qa[2].y * k2.y;
      float da1 = qa[0].x * k0.z + qa[0].y * k0.w + qa[1].x * k1.z + qa[1].y * k1.w +
                  qa[2].x * k2.z + qa[2].y * k2.w;
      float db0 = qb[0].x * k0.x + qb[0].y * k0.y + qb[1].x * k1.x + qb[1].y * k1.y +
                  qb[2].x * k2.x + qb[2].y * k2.y;
      float db1 = qb[0].x * k0.z + qb[0].y * k0.w + qb[1].x * k1.z + qb[1].y * k1.w +
                  qb[2].x * k2.z + qb[2].y * k2.w;
      da0 = __expf(da0); da1 = __expf(da1);
      db0 = __expf(db0); db1 = __expf(db1);
      sva[2 * it] = da0; sva[2 * it + 1] = da1;
      svb[2 * it] = db0; svb[2 * it + 1] = db1;
      suma += da0 + da1;
      sumb += db0 + db1;
    }
    float inva = 1.f / wsum(suma);
    float invb = 1.f / wsum(sumb);
    float aa[6] = {0, 0, 0, 0, 0, 0}, ab[6] = {0, 0, 0, 0, 0, 0};
    vfloat2* arowa = (vfloat2*)(attn + (size_t)(bh * N + qbase) * N);
    vfloat2* arowb = (vfloat2*)(attn + (size_t)(bh * N + qbase + 1) * N);
#pragma unroll
    for (int it = 0; it < 8; ++it) {
      int j = (it << 6) + lane;
      float4 v0 = vt4[j], v1 = vt4[512 + j], v2 = vt4[1024 + j];
      float pa0 = sva[2 * it] * inva, pa1 = sva[2 * it + 1] * inva;
      float pb0 = svb[2 * it] * invb, pb1 = svb[2 * it + 1] * invb;
      vfloat2 sa = {pa0, pa1}, sb = {pb0, pb1};
      __builtin_nontemporal_store(sa, arowa + j);
      __builtin_nontemporal_store(sb, arowb + j);
      aa[0] += pa0 * v0.x + pa1 * v0.z; aa[1] += pa0 * v0.y + pa1 * v0.w;
      aa[2] += pa0 * v1.x + pa1 * v1.z; aa[3] += pa0 * v1.y + pa1 * v1.w;
      aa[4] += pa0 * v2.x + pa1 * v2.z; aa[5] += pa0 * v2.y + pa1 * v2.w;
      ab[0] += pb0 * v0.x + pb1 * v0.z; ab[1] += pb0 * v0.y + pb1 * v0.w;
      ab[2] += pb0 * v1.x + pb1 * v1.z; ab[3] += pb0 * v1.y + pb1 * v1.w;
      ab[4] += pb0 * v2.x + pb1 * v2.z; ab[5] += pb0 * v2.y + pb1 * v2.w;
    }
#pragma unroll
    for (int d = 0; d < 6; ++d) {
      aa[d] = wsum(aa[d]);
      ab[d] = wsum(ab[d]);
    }
    if (lane == 0) {
      int li = wave * 16 + t2 * 2;
#pragma unroll
      for (int d = 0; d < 6; ++d) { ob[li][d] = aa[d]; ob[li + 1][d] = ab[d]; }
    }
  }
  // ---- phase 2: local window attention; wave's 16 rows == one window ----
  int n0 = r0;                  // window base
  int kk = lane & 15, g = lane >> 4;
  float kv[6], vv[6];
#pragma unroll
  for (int d = 0; d < 6; ++d) {
    int a = (d >> 1) * 2048 + ((n0 + kk) << 1) + (d & 1);
    kv[d] = ktf[a];
    vv[d] = vtf[a];
  }
#pragma unroll
  for (int pass = 0; pass < 4; ++pass) {
    int qr2 = n0 + pass * 4 + g;
    const float* qp = q + (bh * N + qr2) * HD;
    float s = 0.f;
#pragma unroll
    for (int d = 0; d < 6; ++d) s += qp[d] * kv[d];
    s *= scl;
    float mx2 = gmax16(s);
    float p = __expf(s - mx2);
    float sum2 = gsum16(p);
    float inv = 1.f / sum2;
    float o[6];
#pragma unroll
    for (int d = 0; d < 6; ++d) o[d] = gsum16(p * vv[d]) * inv;
    if (kk == 0) {
      int li = wave * 16 + pass * 4 + g;
      float* dst = xgl + (size_t)(b * N + qr2) * C + hh * HD;
#pragma unroll
      for (int d = 0; d < 6; ++d) dst[d] = ob[li][d] + o[d];
    }
  }
}

// ------- kernel 3: proj + residual + LN2 + KAN1 + KAN2 + residual --------
__global__ __launch_bounds__(512) void k_mlp(
    const float* __restrict__ x, const float* __restrict__ xgl,
    const float* __restrict__ wp, const float* __restrict__ bp,
    const float* __restrict__ g2, const float* __restrict__ b2,
    const float* __restrict__ bw1, const float* __restrict__ sw1, const float* __restrict__ ss1,
    const float* __restrict__ bw2, const float* __restrict__ sw2, const float* __restrict__ ss2,
    float* __restrict__ x2) {
  __shared__ float wpl[C * 49];          // [o][i]
  __shared__ float bw1t[C * 25];         // [i][o], o<24
  __shared__ float ss1t[C * 25];
  __shared__ float sw1t[C * KB * 25];    // [i*8+k][o]
  __shared__ float bw2t[HID * 49];       // [i][o], o<48
  __shared__ float ss2t[HID * 49];
  __shared__ float sw2t[HID * KB * 49];  // [i*8+k][o]
  __shared__ float abuf[8][2][C];
  __shared__ float sil1[8][2][C];
  __shared__ float bas1[8][2][C][KB];
  __shared__ float sil2[8][2][HID];
  __shared__ float bas2[8][2][HID][KB];
  int tid = threadIdx.x;
  for (int e = tid; e < C * C; e += 512) wpl[(e / C) * 49 + (e % C)] = wp[e];
  for (int e = tid; e < HID * C; e += 512) {
    int o = e / C, i = e - o * C;
    bw1t[i * 25 + o] = bw1[e];
    ss1t[i * 25 + o] = ss1[e];
  }
  for (int e = tid; e < HID * C * KB; e += 512) {
    int o = e / (C * KB), r = e - o * (C * KB);
    sw1t[r * 25 + o] = sw1[e];
  }
  for (int e = tid; e < C * HID; e += 512) {
    int o = e / HID, i = e - o * HID;
    bw2t[i * 49 + o] = bw2[e];
    ss2t[i * 49 + o] = ss2[e];
  }
  for (int e = tid; e < C * HID * KB; e += 512) {
    int o = e / (HID * KB), r = e - o * (HID * KB);
    sw2t[r * 49 + o] = sw2[e];
  }
  __syncthreads();
  int wave = tid >> 6, lane = tid & 63;
  int tok0 = blockIdx.x * 16 + wave * 2;
  float x1v[2];
  // ---- phase A: proj + residual + LN2 + bases (per token) ----
#pragma unroll
  for (int tt = 0; tt < 2; ++tt) {
    int tok = tok0 + tt;
    float acc = 0.f, xin = 0.f;
    if (lane < C) {
      abuf[wave][tt][lane] = xgl[tok * C + lane];
      xin = x[tok * C + lane];
    }
    if (lane < C) {
      acc = bp[lane];
#pragma unroll
      for (int i = 0; i < C; ++i) acc += abuf[wave][tt][i] * wpl[lane * 49 + i];
    }
    float xv = (lane < C) ? xin + acc : 0.f;
    x1v[tt] = xv;
    float s = wsum(xv), s2 = wsum(xv * xv);
    float mean = s * (1.f / C), var = s2 * (1.f / C) - mean * mean;
    float rstd = rsqrtf(var + 1e-5f);
    if (lane < C) {
      float n2v = (xv - mean) * rstd * g2[lane] + b2[lane];
      sil1[wave][tt][lane] = n2v / (1.f + __expf(-n2v));
      float bs[KB];
      bspline8(n2v, bs);
#pragma unroll
      for (int kk = 0; kk < KB; ++kk) bas1[wave][tt][lane][kk] = bs[kk];
    }
  }
  // ---- phase B: KAN1 (48 -> 24), both tokens share weight reads ----
  int o = lane & 31, hf = lane >> 5;
  float h0 = 0.f, h1 = 0.f;
  if (o < HID) {
#pragma unroll 4
    for (int ii = 0; ii < 24; ++ii) {
      int i = hf * 24 + ii;
      float bwv = bw1t[i * 25 + o], ssv = ss1t[i * 25 + o];
      float sp0 = 0.f, sp1 = 0.f;
#pragma unroll
      for (int kk = 0; kk < KB; ++kk) {
        float w = sw1t[(i * KB + kk) * 25 + o];
        sp0 += bas1[wave][0][i][kk] * w;
        sp1 += bas1[wave][1][i][kk] * w;
      }
      h0 += sil1[wave][0][i] * bwv + ssv * sp0;
      h1 += sil1[wave][1][i] * bwv + ssv * sp1;
    }
  }
  h0 += __shfl_xor(h0, 32, 64);
  h1 += __shfl_xor(h1, 32, 64);
  if (lane < HID) {
    float hv[2] = {h0, h1};
#pragma unroll
    for (int tt = 0; tt < 2; ++tt) {
      sil2[wave][tt][lane] = hv[tt] / (1.f + __expf(-hv[tt]));
      float bs[KB];
      bspline8(hv[tt], bs);
#pragma unroll
      for (int kk = 0; kk < KB; ++kk) bas2[wave][tt][lane][kk] = bs[kk];
    }
  }
  // ---- phase C: KAN2 (24 -> 48) + residual ----
  if (lane < C) {
    float a0 = 0.f, a1 = 0.f;
#pragma unroll 4
    for (int i = 0; i < HID; ++i) {
      float bwv = bw2t[i * 49 + lane], ssv = ss2t[i * 49 + lane];
      float sp0 = 0.f, sp1 = 0.f;
#pragma unroll
      for (int kk = 0; kk < KB; ++kk) {
        float w = sw2t[(i * KB + kk) * 49 + lane];
        sp0 += bas2[wave][0][i][kk] * w;
        sp1 += bas2[wave][1][i][kk] * w;
      }
      a0 += sil2[wave][0][i] * bwv + ssv * sp0;
      a1 += sil2[wave][1][i] * bwv + ssv * sp1;
    }
    x2[(size_t)tok0 * C + lane] = x1v[0] + a0;
    x2[(size_t)(tok0 + 1) * C + lane] = x1v[1] + a1;
  }
}

// ---------------- kernel 4: conv1 (48 -> 128, k=3) -----------------------
__global__ __launch_bounds__(256) void k_conv1(
    const float* __restrict__ x, const float* __restrict__ w1, const float* __restrict__ bc1,
    float* __restrict__ h1) {
  __shared__ float wt[72 * C1];  // [i3][o] for one i-half
  __shared__ float xr[18 * C];
  int tid = threadIdx.x;
  int b = blockIdx.x >> 6;
  int t0 = (blockIdx.x & 63) << 4;
  for (int e = tid; e < 18 * C; e += 256) {
    int r = e / C, c = e - r * C;
    int n = t0 - 1 + r;
    xr[e] = (n >= 0 && n < N) ? x[(b * N + n) * C + c] : 0.f;
  }
  int wave = tid >> 6, lane = tid & 63;
  int tb = wave << 2;
  float acc0[4] = {0, 0, 0, 0}, acc1[4] = {0, 0, 0, 0};
  for (int hf = 0; hf < 2; ++hf) {
    __syncthreads();
    for (int e = tid; e < 72 * C1; e += 256) {
      int i3 = e >> 7, o = e & 127;
      int ii = i3 / 3, dk = i3 - ii * 3;
      wt[e] = w1[(o * C + hf * 24 + ii) * 3 + dk];
    }
    __syncthreads();
#pragma unroll 4
    for (int ii = 0; ii < 24; ++ii) {
      float xv[6];
#pragma unroll
      for (int j = 0; j < 6; ++j) xv[j] = xr[(tb + j) * C + hf * 24 + ii];
#pragma unroll
      for (int dk = 0; dk < 3; ++dk) {
        float w0 = wt[(ii * 3 + dk) * C1 + lane];
        float w1v = wt[(ii * 3 + dk) * C1 + 64 + lane];
#pragma unroll
        for (int tt = 0; tt < 4; ++tt) {
          float xi = xv[tt + dk];
          acc0[tt] += xi * w0;
          acc1[tt] += xi * w1v;
        }
      }
    }
  }
  float bb0 = bc1[lane], bb1 = bc1[64 + lane];
#pragma unroll
  for (int tt = 0; tt < 4; ++tt) {
    int n = t0 + tb + tt;
    h1[(b * N + n) * C1 + lane] = acc0[tt] + bb0;
    h1[(b * N + n) * C1 + 64 + lane] = acc1[tt] + bb1;
  }
}

// ---------------- kernel 5: conv2 + LN(g1,b1) + sc*h + x2 -> out ---------
__global__ __launch_bounds__(256) void k_conv2out(
    const float* __restrict__ h1, const float* __restrict__ w3, const float* __restrict__ bc3,
    const float* __restrict__ g1, const float* __restrict__ b1,
    const float* __restrict__ x2, const float* __restrict__ scp,
    float* __restrict__ out) {
  __shared__ float wt[192 * C + 16];  // [i3][c] for one i-half (+pad)
  __shared__ float hr[18 * C1];
  int tid = threadIdx.x;
  int b = blockIdx.x >> 6;
  int t0 = (blockIdx.x & 63) << 4;
  for (int e = tid; e < 18 * C1; e += 256) {
    int r = e >> 7, c = e & 127;
    int n = t0 - 1 + r;
    hr[e] = (n >= 0 && n < N) ? h1[(b * N + n) * C1 + c] : 0.f;
  }
  int wave = tid >> 6, lane = tid & 63;
  int tb = wave << 2;
  float acc[4] = {0, 0, 0, 0};
  for (int hf = 0; hf < 2; ++hf) {
    __syncthreads();
    for (int e = tid; e < 192 * C; e += 256) {
      int i3 = e / C, c = e - i3 * C;
      int ii = i3 / 3, dk = i3 - ii * 3;
      wt[e] = w3[(c * C1 + hf * 64 + ii) * 3 + dk];
    }
    __syncthreads();
#pragma unroll 4
    for (int ii = 0; ii < 64; ++ii) {
      float xv[6];
#pragma unroll
      for (int j = 0; j < 6; ++j) xv[j] = hr[(tb + j) * C1 + hf * 64 + ii];
#pragma unroll
      for (int dk = 0; dk < 3; ++dk) {
        float w = wt[(ii * 3 + dk) * C + lane];
#pragma unroll
        for (int tt = 0; tt < 4; ++tt) acc[tt] += xv[tt + dk] * w;
      }
    }
  }
  float sc0 = scp[0];
#pragma unroll
  for (int tt = 0; tt < 4; ++tt) {
    int n = t0 + tb + tt;
    float val = (lane < C) ? acc[tt] + bc3[lane] : 0.f;
    float s = wsum(val), s2 = wsum(val * val);
    float mean = s * (1.f / C), var = s2 * (1.f / C) - mean * mean;
    float rstd = rsqrtf(var + 1e-5f);
    if (lane < C) {
      float hn = (val - mean) * rstd * g1[lane] + b1[lane];
      out[(b * N + n) * C + lane] = sc0 * hn + x2[(size_t)(b * N + n) * C + lane];
    }
  }
}

extern "C" void kernel_launch(void* const* d_in, const int* in_sizes, int n_in,
                              void* d_out, int out_size, void* d_ws, size_t ws_size,
                              hipStream_t stream) {
  (void)in_sizes; (void)n_in; (void)out_size; (void)ws_size;
  const float* x    = (const float*)d_in[0];
  const float* g1   = (const float*)d_in[1];
  const float* b1   = (const float*)d_in[2];
  const float* wqkv = (const float*)d_in[3];
  const float* wp   = (const float*)d_in[4];
  const float* bp   = (const float*)d_in[5];
  const float* g2   = (const float*)d_in[6];
  const float* b2   = (const float*)d_in[7];
  const float* bw1  = (const float*)d_in[8];
  const float* sw1  = (const float*)d_in[9];
  const float* ss1  = (const float*)d_in[10];
  const float* bw2  = (const float*)d_in[11];
  const float* sw2  = (const float*)d_in[12];
  const float* ss2  = (const float*)d_in[13];
  const float* w1   = (const float*)d_in[14];
  const float* bc1  = (const float*)d_in[15];
  const float* w3   = (const float*)d_in[16];
  const float* bc3  = (const float*)d_in[17];
  const float* scp  = (const float*)d_in[18];

  float* out  = (float*)d_out;
  float* attn = out + (size_t)NT * C;  // out first, then attn_global

  float* ws   = (float*)d_ws;
  float* q    = ws;                 // 393216
  float* k    = ws + 393216;
  float* v    = ws + 786432;
  float* xgl  = ws + 1179648;       // global+local attn output (B,N,C)
  float* x2   = ws + 1572864;
  float* h1   = ws + 1966080;       // (B,N,128) = 1048576

  k_ln_qkv<<<NT / 8, 256, 0, stream>>>(x, g1, b1, wqkv, q, k, v);
  k_gattn<<<B * H * 16, 256, 0, stream>>>(q, k, v, attn, xgl);
  k_mlp<<<NT / 16, 512, 0, stream>>>(x, xgl, wp, bp, g2, b2,
                                     bw1, sw1, ss1, bw2, sw2, ss2, x2);
  k_conv1<<<512, 256, 0, stream>>>(x, w1, bc1, h1);
  k_conv2out<<<512, 256, 0, stream>>>(h1, w3, bc3, g1, b1, x2, scp, out);
}

// Round 8
// 452.973 us; speedup vs baseline: 1.2385x; 1.0670x over previous
//
#include <hip/hip_runtime.h>

static constexpr int B = 8, N = 1024, C = 48, H = 8, HD = 6, NT = B * N; // 8192 tokens
static constexpr int QKVO = 3 * C;   // 144
static constexpr int HID = 24, KB = 8;
static constexpr int C1 = 128;

typedef float vfloat2 __attribute__((ext_vector_type(2)));  // clang-native, NT-store OK

#define DEVFN __device__ __forceinline__

DEVFN float wsum(float v) {
#pragma unroll
  for (int m = 32; m; m >>= 1) v += __shfl_xor(v, m, 64);
  return v;
}
DEVFN float gsum16(float v) {
#pragma unroll
  for (int m = 8; m; m >>= 1) v += __shfl_xor(v, m, 16);
  return v;
}
DEVFN float gmax16(float v) {
#pragma unroll
  for (int m = 8; m; m >>= 1) v = fmaxf(v, __shfl_xor(v, m, 16));
  return v;
}

// Wave64 sum via DPP (VALU pipe, not LDS). Result valid in lane 63.
DEVFN float wsum64_l63(float v) {
  float t;
  t = __int_as_float(__builtin_amdgcn_update_dpp(0, __float_as_int(v), 0x111, 0xF, 0xF, true)); v += t; // row_shr:1
  t = __int_as_float(__builtin_amdgcn_update_dpp(0, __float_as_int(v), 0x112, 0xF, 0xF, true)); v += t; // row_shr:2
  t = __int_as_float(__builtin_amdgcn_update_dpp(0, __float_as_int(v), 0x114, 0xF, 0xF, true)); v += t; // row_shr:4
  t = __int_as_float(__builtin_amdgcn_update_dpp(0, __float_as_int(v), 0x118, 0xF, 0xF, true)); v += t; // row_shr:8
  t = __int_as_float(__builtin_amdgcn_update_dpp(0, __float_as_int(v), 0x142, 0xA, 0xF, true)); v += t; // row_bcast15
  t = __int_as_float(__builtin_amdgcn_update_dpp(0, __float_as_int(v), 0x143, 0xC, 0xF, true)); v += t; // row_bcast31
  return v;
}
DEVFN float wsum64_bcast(float v) {
  return __int_as_float(__builtin_amdgcn_readlane(__float_as_int(wsum64_l63(v)), 63));
}

// Cubic B-spline bases, GRID_SIZE=5, order=3, knots -2.2 + 0.4*j, j=0..11.
DEVFN void bspline8(float x, float* bs) {
  float b[11];
#pragma unroll
  for (int j = 0; j < 11; ++j) {
    float gj = -2.2f + 0.4f * j;
    float gj1 = -2.2f + 0.4f * (j + 1);
    b[j] = (x >= gj && x < gj1) ? 1.0f : 0.0f;
  }
#pragma unroll
  for (int j = 0; j < 10; ++j) {
    float gj = -2.2f + 0.4f * j;
    b[j] = (x - gj) * 2.5f * b[j] + ((gj + 0.8f) - x) * 2.5f * b[j + 1];
  }
#pragma unroll
  for (int j = 0; j < 9; ++j) {
    float gj = -2.2f + 0.4f * j;
    b[j] = (x - gj) * 1.25f * b[j] + ((gj + 1.2f) - x) * 1.25f * b[j + 1];
  }
#pragma unroll
  for (int j = 0; j < 8; ++j) {
    float gj = -2.2f + 0.4f * j;
    bs[j] = (x - gj) * (1.0f / 1.2f) * b[j] + ((gj + 1.6f) - x) * (1.0f / 1.2f) * b[j + 1];
  }
}

// ---------------- kernel 1: LN1 + QKV projection (2 tokens/wave) ---------
__global__ __launch_bounds__(256) void k_ln_qkv(
    const float* __restrict__ x, const float* __restrict__ g1, const float* __restrict__ b1,
    const float* __restrict__ wqkv, float* __restrict__ q, float* __restrict__ k,
    float* __restrict__ v) {
  __shared__ float wl[QKVO * 49];   // [o][i], stride 49 -> conflict-free
  __shared__ float nb[4][2][C];
  int tid = threadIdx.x;
  for (int e = tid; e < QKVO * C; e += 256) wl[(e / C) * 49 + (e % C)] = wqkv[e];
  int wave = tid >> 6, lane = tid & 63;
  int tok0 = blockIdx.x * 8 + wave * 2;
#pragma unroll
  for (int tt = 0; tt < 2; ++tt) {
    const float* xr = x + (tok0 + tt) * C;
    float xv = (lane < C) ? xr[lane] : 0.f;
    float s = wsum(xv), s2 = wsum(xv * xv);
    float mean = s * (1.f / C);
    float var = s2 * (1.f / C) - mean * mean;
    float rstd = rsqrtf(var + 1e-5f);
    if (lane < C) nb[wave][tt][lane] = (xv - mean) * rstd * g1[lane] + b1[lane];
  }
  __syncthreads();
  int b = tok0 >> 10, n0 = tok0 & 1023;
#pragma unroll
  for (int r = 0; r < 3; ++r) {
    int o = lane + (r << 6);
    if (o < QKVO) {
      float a0 = 0.f, a1 = 0.f;
#pragma unroll
      for (int i = 0; i < C; ++i) {
        float w = wl[o * 49 + i];
        a0 += nb[wave][0][i] * w;
        a1 += nb[wave][1][i] * w;
      }
      int ssel = o / C;
      int rem = o - ssel * C;
      int hh = rem / HD;
      int d = rem - hh * HD;
      float* dst = ssel == 0 ? q : (ssel == 1 ? k : v);
      dst[((b * H + hh) * N + n0) * HD + d] = a0;
      dst[((b * H + hh) * N + n0 + 1) * HD + d] = a1;
    }
  }
}

// ------- kernel 2: global attention + probs + local attention ------------
__global__ __launch_bounds__(256) void k_gattn(
    const float* __restrict__ q, const float* __restrict__ k, const float* __restrict__ v,
    float* __restrict__ attn, float* __restrict__ xgl) {
  __shared__ float2 kt[3][N];   // kt[dp][kp] = {K[kp][2dp], K[kp][2dp+1]}
  __shared__ float2 vt[3][N];
  __shared__ float ob[64][6];   // per-row global-attn output
  int tid = threadIdx.x;
  int bh = blockIdx.x >> 4;     // 1024 blocks: 64 rows each
  int rb = blockIdx.x & 15;
  const float* kg = k + bh * N * HD;
  const float* vg = v + bh * N * HD;
  float* ktf = (float*)kt;
  float* vtf = (float*)vt;
  for (int e = tid; e < N * HD; e += 256) {
    int kp = e / 6, d = e - kp * 6;
    int a = (d >> 1) * 2048 + (kp << 1) + (d & 1);
    ktf[a] = kg[e];
    vtf[a] = vg[e];
  }
  __syncthreads();
  int wave = tid >> 6, lane = tid & 63;
  const float scl = 0.40824829046386301637f;  // 6^-0.5
  int b = bh >> 3, hh = bh & 7;
  int r0 = rb * 64 + wave * 16;
  const float4* kt4 = (const float4*)ktf;  // [dp*512 + j]: dims(2dp,2dp+1) x pos(2j,2j+1)
  const float4* vt4 = (const float4*)vtf;
  // ---- phase 1: global attention, 4 tiles of 4 rows; 2 k-pos per lane ----
#pragma unroll 1
  for (int t4 = 0; t4 < 4; ++t4) {
    int qbase = r0 + t4 * 4;
    float2 qr[4][3];
#pragma unroll
    for (int r = 0; r < 4; ++r) {
      const float2* qp = (const float2*)(q + (bh * N + qbase + r) * HD);
      qr[r][0] = qp[0]; qr[r][1] = qp[1]; qr[r][2] = qp[2];
#pragma unroll
      for (int d = 0; d < 3; ++d) { qr[r][d].x *= scl; qr[r][d].y *= scl; }
    }
    float sv[4][16];
    float sum[4] = {0.f, 0.f, 0.f, 0.f};
#pragma unroll
    for (int it = 0; it < 8; ++it) {
      int j = (it << 6) + lane;
      float4 k0 = kt4[j], k1 = kt4[512 + j], k2 = kt4[1024 + j];
#pragma unroll
      for (int r = 0; r < 4; ++r) {
        float d0 = qr[r][0].x * k0.x + qr[r][0].y * k0.y + qr[r][1].x * k1.x +
                   qr[r][1].y * k1.y + qr[r][2].x * k2.x + qr[r][2].y * k2.y;
        float d1 = qr[r][0].x * k0.z + qr[r][0].y * k0.w + qr[r][1].x * k1.z +
                   qr[r][1].y * k1.w + qr[r][2].x * k2.z + qr[r][2].y * k2.w;
        d0 = __expf(d0); d1 = __expf(d1);
        sv[r][2 * it] = d0; sv[r][2 * it + 1] = d1;
        sum[r] += d0 + d1;
      }
    }
    float inv[4];
#pragma unroll
    for (int r = 0; r < 4; ++r) inv[r] = 1.f / wsum64_bcast(sum[r]);
    float acc[4][6];
#pragma unroll
    for (int r = 0; r < 4; ++r)
#pragma unroll
      for (int d = 0; d < 6; ++d) acc[r][d] = 0.f;
#pragma unroll
    for (int it = 0; it < 8; ++it) {
      int j = (it << 6) + lane;
      float4 v0 = vt4[j], v1 = vt4[512 + j], v2 = vt4[1024 + j];
#pragma unroll
      for (int r = 0; r < 4; ++r) {
        float p0 = sv[r][2 * it] * inv[r];
        float p1 = sv[r][2 * it + 1] * inv[r];
        vfloat2 s2v = {p0, p1};
        __builtin_nontemporal_store(s2v, (vfloat2*)(attn + (size_t)(bh * N + qbase + r) * N) + j);
        acc[r][0] += p0 * v0.x + p1 * v0.z; acc[r][1] += p0 * v0.y + p1 * v0.w;
        acc[r][2] += p0 * v1.x + p1 * v1.z; acc[r][3] += p0 * v1.y + p1 * v1.w;
        acc[r][4] += p0 * v2.x + p1 * v2.z; acc[r][5] += p0 * v2.y + p1 * v2.w;
      }
    }
#pragma unroll
    for (int r = 0; r < 4; ++r)
#pragma unroll
      for (int d = 0; d < 6; ++d) acc[r][d] = wsum64_l63(acc[r][d]);
    if (lane == 63) {
      int li = wave * 16 + t4 * 4;
#pragma unroll
      for (int r = 0; r < 4; ++r)
#pragma unroll
        for (int d = 0; d < 6; ++d) ob[li + r][d] = acc[r][d];
    }
  }
  // ---- phase 2: local window attention; wave's 16 rows == one window ----
  int n0 = r0;                  // window base
  int kk = lane & 15, g = lane >> 4;
  float kv[6], vv[6];
#pragma unroll
  for (int d = 0; d < 6; ++d) {
    int a = (d >> 1) * 2048 + ((n0 + kk) << 1) + (d & 1);
    kv[d] = ktf[a];
    vv[d] = vtf[a];
  }
#pragma unroll
  for (int pass = 0; pass < 4; ++pass) {
    int qr2 = n0 + pass * 4 + g;
    const float* qp = q + (bh * N + qr2) * HD;
    float s = 0.f;
#pragma unroll
    for (int d = 0; d < 6; ++d) s += qp[d] * kv[d];
    s *= scl;
    float mx2 = gmax16(s);
    float p = __expf(s - mx2);
    float sum2 = gsum16(p);
    float inv2 = 1.f / sum2;
    float o[6];
#pragma unroll
    for (int d = 0; d < 6; ++d) o[d] = gsum16(p * vv[d]) * inv2;
    if (kk == 0) {
      int li = wave * 16 + pass * 4 + g;
      float* dst = xgl + (size_t)(b * N + qr2) * C + hh * HD;
#pragma unroll
      for (int d = 0; d < 6; ++d) dst[d] = ob[li][d] + o[d];
    }
  }
}

// ------- kernel 3: proj + residual + LN2 + KAN1 + KAN2 + residual --------
__global__ __launch_bounds__(512) void k_mlp(
    const float* __restrict__ x, const float* __restrict__ xgl,
    const float* __restrict__ wp, const float* __restrict__ bp,
    const float* __restrict__ g2, const float* __restrict__ b2,
    const float* __restrict__ bw1, const float* __restrict__ sw1, const float* __restrict__ ss1,
    const float* __restrict__ bw2, const float* __restrict__ sw2, const float* __restrict__ ss2,
    float* __restrict__ x2) {
  __shared__ float wpl[C * 49];          // [o][i]
  __shared__ float bw1t[C * 25];         // [i][o], o<24
  __shared__ float ss1t[C * 25];
  __shared__ float sw1t[C * KB * 25];    // [i*8+k][o]
  __shared__ float bw2t[HID * 49];       // [i][o], o<48
  __shared__ float ss2t[HID * 49];
  __shared__ float sw2t[HID * KB * 49];  // [i*8+k][o]
  __shared__ float abuf[8][2][C];
  __shared__ float sil1[8][2][C];
  __shared__ float bas1[8][2][C][KB];
  __shared__ float sil2[8][2][HID];
  __shared__ float bas2[8][2][HID][KB];
  int tid = threadIdx.x;
  for (int e = tid; e < C * C; e += 512) wpl[(e / C) * 49 + (e % C)] = wp[e];
  for (int e = tid; e < HID * C; e += 512) {
    int o = e / C, i = e - o * C;
    bw1t[i * 25 + o] = bw1[e];
    ss1t[i * 25 + o] = ss1[e];
  }
  for (int e = tid; e < HID * C * KB; e += 512) {
    int o = e / (C * KB), r = e - o * (C * KB);
    sw1t[r * 25 + o] = sw1[e];
  }
  for (int e = tid; e < C * HID; e += 512) {
    int o = e / HID, i = e - o * HID;
    bw2t[i * 49 + o] = bw2[e];
    ss2t[i * 49 + o] = ss2[e];
  }
  for (int e = tid; e < C * HID * KB; e += 512) {
    int o = e / (HID * KB), r = e - o * (HID * KB);
    sw2t[r * 49 + o] = sw2[e];
  }
  __syncthreads();
  int wave = tid >> 6, lane = tid & 63;
  int tok0 = blockIdx.x * 16 + wave * 2;
  float x1v[2];
  // ---- phase A: proj + residual + LN2 + bases (per token) ----
#pragma unroll
  for (int tt = 0; tt < 2; ++tt) {
    int tok = tok0 + tt;
    float acc = 0.f, xin = 0.f;
    if (lane < C) {
      abuf[wave][tt][lane] = xgl[tok * C + lane];
      xin = x[tok * C + lane];
    }
    if (lane < C) {
      acc = bp[lane];
#pragma unroll
      for (int i = 0; i < C; ++i) acc += abuf[wave][tt][i] * wpl[lane * 49 + i];
    }
    float xv = (lane < C) ? xin + acc : 0.f;
    x1v[tt] = xv;
    float s = wsum(xv), s2 = wsum(xv * xv);
    float mean = s * (1.f / C), var = s2 * (1.f / C) - mean * mean;
    float rstd = rsqrtf(var + 1e-5f);
    if (lane < C) {
      float n2v = (xv - mean) * rstd * g2[lane] + b2[lane];
      sil1[wave][tt][lane] = n2v / (1.f + __expf(-n2v));
      float bs[KB];
      bspline8(n2v, bs);
#pragma unroll
      for (int kk = 0; kk < KB; ++kk) bas1[wave][tt][lane][kk] = bs[kk];
    }
  }
  // ---- phase B: KAN1 (48 -> 24), both tokens share weight reads ----
  int o = lane & 31, hf = lane >> 5;
  float h0 = 0.f, h1 = 0.f;
  if (o < HID) {
#pragma unroll 4
    for (int ii = 0; ii < 24; ++ii) {
      int i = hf * 24 + ii;
      float bwv = bw1t[i * 25 + o], ssv = ss1t[i * 25 + o];
      float sp0 = 0.f, sp1 = 0.f;
#pragma unroll
      for (int kk = 0; kk < KB; ++kk) {
        float w = sw1t[(i * KB + kk) * 25 + o];
        sp0 += bas1[wave][0][i][kk] * w;
        sp1 += bas1[wave][1][i][kk] * w;
      }
      h0 += sil1[wave][0][i] * bwv + ssv * sp0;
      h1 += sil1[wave][1][i] * bwv + ssv * sp1;
    }
  }
  h0 += __shfl_xor(h0, 32, 64);
  h1 += __shfl_xor(h1, 32, 64);
  if (lane < HID) {
    float hv[2] = {h0, h1};
#pragma unroll
    for (int tt = 0; tt < 2; ++tt) {
      sil2[wave][tt][lane] = hv[tt] / (1.f + __expf(-hv[tt]));
      float bs[KB];
      bspline8(hv[tt], bs);
#pragma unroll
      for (int kk = 0; kk < KB; ++kk) bas2[wave][tt][lane][kk] = bs[kk];
    }
  }
  // ---- phase C: KAN2 (24 -> 48) + residual ----
  if (lane < C) {
    float a0 = 0.f, a1 = 0.f;
#pragma unroll 4
    for (int i = 0; i < HID; ++i) {
      float bwv = bw2t[i * 49 + lane], ssv = ss2t[i * 49 + lane];
      float sp0 = 0.f, sp1 = 0.f;
#pragma unroll
      for (int kk = 0; kk < KB; ++kk) {
        float w = sw2t[(i * KB + kk) * 49 + lane];
        sp0 += bas2[wave][0][i][kk] * w;
        sp1 += bas2[wave][1][i][kk] * w;
      }
      a0 += sil2[wave][0][i] * bwv + ssv * sp0;
      a1 += sil2[wave][1][i] * bwv + ssv * sp1;
    }
    x2[(size_t)tok0 * C + lane] = x1v[0] + a0;
    x2[(size_t)(tok0 + 1) * C + lane] = x1v[1] + a1;
  }
}

// ---------------- kernel 4: conv1 (48 -> 128, k=3) -----------------------
__global__ __launch_bounds__(256) void k_conv1(
    const float* __restrict__ x, const float* __restrict__ w1, const float* __restrict__ bc1,
    float* __restrict__ h1) {
  __shared__ float wt[72 * C1];  // [i3][o] for one i-half
  __shared__ float xr[18 * C];
  int tid = threadIdx.x;
  int b = blockIdx.x >> 6;
  int t0 = (blockIdx.x & 63) << 4;
  for (int e = tid; e < 18 * C; e += 256) {
    int r = e / C, c = e - r * C;
    int n = t0 - 1 + r;
    xr[e] = (n >= 0 && n < N) ? x[(b * N + n) * C + c] : 0.f;
  }
  int wave = tid >> 6, lane = tid & 63;
  int tb = wave << 2;
  float acc0[4] = {0, 0, 0, 0}, acc1[4] = {0, 0, 0, 0};
  for (int hf = 0; hf < 2; ++hf) {
    __syncthreads();
    for (int e = tid; e < 72 * C1; e += 256) {
      int i3 = e >> 7, o = e & 127;
      int ii = i3 / 3, dk = i3 - ii * 3;
      wt[e] = w1[(o * C + hf * 24 + ii) * 3 + dk];
    }
    __syncthreads();
#pragma unroll 4
    for (int ii = 0; ii < 24; ++ii) {
      float xv[6];
#pragma unroll
      for (int j = 0; j < 6; ++j) xv[j] = xr[(tb + j) * C + hf * 24 + ii];
#pragma unroll
      for (int dk = 0; dk < 3; ++dk) {
        float w0 = wt[(ii * 3 + dk) * C1 + lane];
        float w1v = wt[(ii * 3 + dk) * C1 + 64 + lane];
#pragma unroll
        for (int tt = 0; tt < 4; ++tt) {
          float xi = xv[tt + dk];
          acc0[tt] += xi * w0;
          acc1[tt] += xi * w1v;
        }
      }
    }
  }
  float bb0 = bc1[lane], bb1 = bc1[64 + lane];
#pragma unroll
  for (int tt = 0; tt < 4; ++tt) {
    int n = t0 + tb + tt;
    h1[(b * N + n) * C1 + lane] = acc0[tt] + bb0;
    h1[(b * N + n) * C1 + 64 + lane] = acc1[tt] + bb1;
  }
}

// ---------------- kernel 5: conv2 + LN(g1,b1) + sc*h + x2 -> out ---------
__global__ __launch_bounds__(256) void k_conv2out(
    const float* __restrict__ h1, const float* __restrict__ w3, const float* __restrict__ bc3,
    const float* __restrict__ g1, const float* __restrict__ b1,
    const float* __restrict__ x2, const float* __restrict__ scp,
    float* __restrict__ out) {
  __shared__ float wt[192 * C + 16];  // [i3][c] for one i-half (+pad)
  __shared__ float hr[18 * C1];
  int tid = threadIdx.x;
  int b = blockIdx.x >> 6;
  int t0 = (blockIdx.x & 63) << 4;
  for (int e = tid; e < 18 * C1; e += 256) {
    int r = e >> 7, c = e & 127;
    int n = t0 - 1 + r;
    hr[e] = (n >= 0 && n < N) ? h1[(b * N + n) * C1 + c] : 0.f;
  }
  int wave = tid >> 6, lane = tid & 63;
  int tb = wave << 2;
  float acc[4] = {0, 0, 0, 0};
  for (int hf = 0; hf < 2; ++hf) {
    __syncthreads();
    for (int e = tid; e < 192 * C; e += 256) {
      int i3 = e / C, c = e - i3 * C;
      int ii = i3 / 3, dk = i3 - ii * 3;
      wt[e] = w3[(c * C1 + hf * 64 + ii) * 3 + dk];
    }
    __syncthreads();
#pragma unroll 4
    for (int ii = 0; ii < 64; ++ii) {
      float xv[6];
#pragma unroll
      for (int j = 0; j < 6; ++j) xv[j] = hr[(tb + j) * C1 + hf * 64 + ii];
#pragma unroll
      for (int dk = 0; dk < 3; ++dk) {
        float w = wt[(ii * 3 + dk) * C + lane];
#pragma unroll
        for (int tt = 0; tt < 4; ++tt) acc[tt] += xv[tt + dk] * w;
      }
    }
  }
  float sc0 = scp[0];
#pragma unroll
  for (int tt = 0; tt < 4; ++tt) {
    int n = t0 + tb + tt;
    float val = (lane < C) ? acc[tt] + bc3[lane] : 0.f;
    float s = wsum(val), s2 = wsum(val * val);
    float mean = s * (1.f / C), var = s2 * (1.f / C) - mean * mean;
    float rstd = rsqrtf(var + 1e-5f);
    if (lane < C) {
      float hn = (val - mean) * rstd * g1[lane] + b1[lane];
      out[(b * N + n) * C + lane] = sc0 * hn + x2[(size_t)(b * N + n) * C + lane];
    }
  }
}

extern "C" void kernel_launch(void* const* d_in, const int* in_sizes, int n_in,
                              void* d_out, int out_size, void* d_ws, size_t ws_size,
                              hipStream_t stream) {
  (void)in_sizes; (void)n_in; (void)out_size; (void)ws_size;
  const float* x    = (const float*)d_in[0];
  const float* g1   = (const float*)d_in[1];
  const float* b1   = (const float*)d_in[2];
  const float* wqkv = (const float*)d_in[3];
  const float* wp   = (const float*)d_in[4];
  const float* bp   = (const float*)d_in[5];
  const float* g2   = (const float*)d_in[6];
  const float* b2   = (const float*)d_in[7];
  const float* bw1  = (const float*)d_in[8];
  const float* sw1  = (const float*)d_in[9];
  const float* ss1  = (const float*)d_in[10];
  const float* bw2  = (const float*)d_in[11];
  const float* sw2  = (const float*)d_in[12];
  const float* ss2  = (const float*)d_in[13];
  const float* w1   = (const float*)d_in[14];
  const float* bc1  = (const float*)d_in[15];
  const float* w3   = (const float*)d_in[16];
  const float* bc3  = (const float*)d_in[17];
  const float* scp  = (const float*)d_in[18];

  float* out  = (float*)d_out;
  float* attn = out + (size_t)NT * C;  // out first, then attn_global

  float* ws   = (float*)d_ws;
  float* q    = ws;                 // 393216
  float* k    = ws + 393216;
  float* v    = ws + 786432;
  float* xgl  = ws + 1179648;       // global+local attn output (B,N,C)
  float* x2   = ws + 1572864;
  float* h1   = ws + 1966080;       // (B,N,128) = 1048576

  k_ln_qkv<<<NT / 8, 256, 0, stream>>>(x, g1, b1, wqkv, q, k, v);
  k_gattn<<<B * H * 16, 256, 0, stream>>>(q, k, v, attn, xgl);
  k_mlp<<<NT / 16, 512, 0, stream>>>(x, xgl, wp, bp, g2, b2,
                                     bw1, sw1, ss1, bw2, sw2, ss2, x2);
  k_conv1<<<512, 256, 0, stream>>>(x, w1, bc1, h1);
  k_conv2out<<<512, 256, 0, stream>>>(h1, w3, bc3, g1, b1, x2, scp, out);
}